// Round 4
// baseline (376.880 us; speedup 1.0000x reference)
//
#include <hip/hip_runtime.h>
#include <stdint.h>

// ---------------- problem constants (from reference) ----------------
#define DIN   4096
#define DOUT  4096
#define RANK  16
#define MTOT  8192            // 4 * 2048
#define LSCALE 2.0f           // alpha/rank = 32/16

typedef unsigned short u16;
typedef __bf16 bf16x8 __attribute__((ext_vector_type(8)));
typedef float  f32x4  __attribute__((ext_vector_type(4)));
typedef u16    u16x8  __attribute__((ext_vector_type(8)));

__device__ __forceinline__ u16 f2bf(float f) {
    uint32_t u = __builtin_bit_cast(uint32_t, f);
    u = (u + 0x7FFFu + ((u >> 16) & 1u)) >> 16;   // RNE
    return (u16)u;
}

__device__ __forceinline__ u16x8 pack8(f32x4 a, f32x4 b) {
    u16x8 o;
    o[0] = f2bf(a[0]); o[1] = f2bf(a[1]); o[2] = f2bf(a[2]); o[3] = f2bf(a[3]);
    o[4] = f2bf(b[0]); o[5] = f2bf(b[1]); o[6] = f2bf(b[2]); o[7] = f2bf(b[3]);
    return o;
}

#define GLDS16(g, l) __builtin_amdgcn_global_load_lds( \
    (const __attribute__((address_space(1))) void*)(g), \
    (__attribute__((address_space(3))) void*)(l), 16, 0, 0)

// ---------------- pass 1a: x (f32) -> xb (bf16) ----------------
__global__ __launch_bounds__(256) void k_convert_x(const float* __restrict__ x,
                                                   u16* __restrict__ xb) {
    long i = ((long)blockIdx.x * 256 + threadIdx.x) * 8;
    f32x4 a = *(const f32x4*)(x + i);
    f32x4 b = *(const f32x4*)(x + i + 4);
    *(u16x8*)(xb + i) = pack8(a, b);
}

// ---------------- pass 1b: W_eff = W + scale * B @ A  (bf16) ----------------
__global__ __launch_bounds__(256) void k_build_weff(const float* __restrict__ W,
                                                    const float* __restrict__ A,
                                                    const float* __restrict__ B,
                                                    u16* __restrict__ wb) {
    long t = (long)blockIdx.x * 256 + threadIdx.x;
    long i = t * 8;
    int o = (int)(i >> 12);        // / DIN
    int d = (int)(i & (DIN - 1));
    float sB[RANK];
#pragma unroll
    for (int r = 0; r < RANK; ++r) sB[r] = B[o * RANK + r] * LSCALE;
    f32x4 w0 = *(const f32x4*)(W + i);
    f32x4 w1 = *(const f32x4*)(W + i + 4);
#pragma unroll
    for (int r = 0; r < RANK; ++r) {
        f32x4 a0 = *(const f32x4*)(A + (long)r * DIN + d);
        f32x4 a1 = *(const f32x4*)(A + (long)r * DIN + d + 4);
        w0 += a0 * sB[r];
        w1 += a1 * sB[r];
    }
    *(u16x8*)(wb + i) = pack8(w0, w1);
}

// ---------------- main GEMM: out = xb @ wb^T + bias ----------------
// 256x256 tile, BK=64, 8 waves. READ-AHEAD pipeline: phase p's MFMA consumes
// frags read in phase p-1; phase p issues reads for p+1. ONE barrier/phase,
// uniform vmcnt(2) gate at each phase start (retires the stage-pair issued
// exactly 2 phases earlier). Stage order per tile: A.lo, B.lo, B.hi, A.hi.
#define BM 256
#define BN 256
#define BK 64
#define NT (DIN / BK)          // 64 K-tiles

#define MFMA16(d, a, b) d = __builtin_amdgcn_mfma_f32_16x16x32_bf16(a, b, d, 0, 0, 0)
#define GATE2() asm volatile("s_waitcnt vmcnt(2)" ::: "memory")
#define ABAR()  asm volatile("s_barrier" ::: "memory")
#define PRIO1() __builtin_amdgcn_s_setprio(1)
#define PRIO0() __builtin_amdgcn_s_setprio(0)

// 4x2 quadrant of 16 MFMAs: acc[mo+m][no+n] += AF[m] x BF[n]  (kk=0,1)
#define QUAD(mo, no, AF, BF) \
    _Pragma("unroll") \
    for (int m = 0; m < 4; ++m) { \
        _Pragma("unroll") \
        for (int n = 0; n < 2; ++n) { \
            MFMA16(acc[(mo)+m][(no)+n], AF[m][0], BF[n][0]); \
            MFMA16(acc[(mo)+m][(no)+n], AF[m][1], BF[n][1]); \
        } \
    }

#define READ_A4(DST, P, RB) \
    _Pragma("unroll") \
    for (int m = 0; m < 4; ++m) { \
        DST[m][0] = *(const bf16x8*)((P) + (RB) + m*1024 + go0); \
        DST[m][1] = *(const bf16x8*)((P) + (RB) + m*1024 + go1); \
    }
#define READ_B2(DST, P, RB) \
    _Pragma("unroll") \
    for (int n = 0; n < 2; ++n) { \
        DST[n][0] = *(const bf16x8*)((P) + (RB) + n*1024 + go0); \
        DST[n][1] = *(const bf16x8*)((P) + (RB) + n*1024 + go1); \
    }

__global__ __launch_bounds__(512, 2) void k_gemm_ws(const u16* __restrict__ xb,
                                                    const u16* __restrict__ wb,
                                                    const float* __restrict__ bias,
                                                    float* __restrict__ out) {
    constexpr int K = DIN, N = DOUT;
    __shared__ alignas(16) u16 lds[65536];   // 128 KiB: A0 A1 B0 B1 slabs of 16384 u16

    // T1: bijective XCD swizzle (gridDim.x = 512, divisible by 8)
    const int nchunk = gridDim.x >> 3;
    const int bid = blockIdx.x;
    const int wg  = (bid & 7) * nchunk + (bid >> 3);
    const int bm  = (wg & 31) * BM;    // 32 m-tiles; consecutive wg share bn
    const int bn  = (wg >> 5) * BN;    // 16 n-tiles

    const int tid  = threadIdx.x;
    const int lane = tid & 63;
    const int wid  = tid >> 6;         // 0..7
    const int wr   = wid >> 2;         // 0..1
    const int wc   = wid & 3;          // 0..3
    const int lrow = lane & 15;
    const int kgrp = lane >> 4;        // 0..3

    // ---- staging geometry (T2: pre-swizzled global source, linear LDS dest) ----
    const int srow = tid >> 3;                       // 0..63
    const int sgl  = (tid & 7) ^ (srow & 7);
    const u16* const aSrcB = xb + (long)(bm + srow) * K + sgl * 8;
    const u16* const bSrcB = wb + (long)(bn + srow) * K + sgl * 8;

    // chunk c covers tile rows 64c..64c+63; A[buf] at buf*16384, B[buf] at 32768+buf*16384
#define STAGE_A(c, buf, kt) GLDS16(aSrcB + (long)(64*(c))*K + (kt)*BK, \
                                   lds + (buf)*16384 + (c)*4096 + tid*8)
#define STAGE_B(c, buf, kt) GLDS16(bSrcB + (long)(64*(c))*K + (kt)*BK, \
                                   lds + 32768 + (buf)*16384 + (c)*4096 + tid*8)

    // ---- fragment-read geometry (swizzled) ----
    const int go0 = (kgrp ^ (lrow & 7)) * 8;   // kk=0 granule
    const int go1 = go0 ^ 32;                  // kk=1: granule ^ 4
    const int arL = (wr*64 + lrow) * 64;       // A.lo row base (u16 units)
    const int arH = arL + 128*64;
    const int brL = (wc*32 + lrow) * 64;       // B.lo row base
    const int brH = brL + 128*64;

    const u16* const pA0 = lds;
    const u16* const pA1 = lds + 16384;
    const u16* const pB0 = lds + 32768;
    const u16* const pB1 = lds + 49152;

    f32x4 acc[8][4];
#pragma unroll
    for (int m = 0; m < 8; ++m)
#pragma unroll
        for (int n = 0; n < 4; ++n) acc[m][n] = (f32x4){0.f, 0.f, 0.f, 0.f};

    bf16x8 afL[4][2], afH[4][2], bfB[2][2], bfAe[2][2], bfAo[2][2];

    // ---- prologue: stage tile 0 into buf0, drain, pre-read Q1(0) frags ----
    STAGE_A(0, 0, 0); STAGE_A(1, 0, 0);
    STAGE_B(0, 0, 0); STAGE_B(1, 0, 0);
    STAGE_B(2, 0, 0); STAGE_B(3, 0, 0);
    STAGE_A(2, 0, 0); STAGE_A(3, 0, 0);
    asm volatile("s_waitcnt vmcnt(0)" ::: "memory");
    ABAR();
    READ_A4(afL, pA0, arL);
    READ_B2(bfAe, pB0, brL);

    for (int it = 0; it < NT/2; ++it) {
        const int tn0 = 2*it + 1;                  // stage target for even tile
        const int tn1 = (2*it + 2) & (NT - 1);     // stage target for odd tile

        // ================= even tile t=2it: compute buf0, stage buf1 =================
        // P1: Q1 = afL x bfAe; read bfB(t); stage A.lo(t+1)
        GATE2(); ABAR();
        READ_B2(bfB, pB0, brH);
        STAGE_A(0, 1, tn0); STAGE_A(1, 1, tn0);
        PRIO1(); QUAD(0, 0, afL, bfAe); PRIO0();

        // P2: Q2 = afL x bfB; read afH(t); stage B.lo(t+1)
        GATE2(); ABAR();
        READ_A4(afH, pA0, arH);
        STAGE_B(0, 1, tn0); STAGE_B(1, 1, tn0);
        PRIO1(); QUAD(0, 2, afL, bfB); PRIO0();

        // P3: Q3 = afH x bfB; read afL(t+1) from buf1; stage B.hi(t+1)
        GATE2(); ABAR();
        READ_A4(afL, pA1, arL);
        STAGE_B(2, 1, tn0); STAGE_B(3, 1, tn0);
        PRIO1(); QUAD(4, 2, afH, bfB); PRIO0();

        // P4: Q4 = afH x bfAe; read bfAo(t+1) from buf1; stage A.hi(t+1)
        GATE2(); ABAR();
        READ_B2(bfAo, pB1, brL);
        STAGE_A(2, 1, tn0); STAGE_A(3, 1, tn0);
        PRIO1(); QUAD(4, 0, afH, bfAe); PRIO0();

        // ================= odd tile t=2it+1: compute buf1, stage buf0 =================
        // P1: Q1 = afL x bfAo; read bfB; stage A.lo(t+2)
        GATE2(); ABAR();
        READ_B2(bfB, pB1, brH);
        STAGE_A(0, 0, tn1); STAGE_A(1, 0, tn1);
        PRIO1(); QUAD(0, 0, afL, bfAo); PRIO0();

        // P2: Q2 = afL x bfB; read afH; stage B.lo(t+2)
        GATE2(); ABAR();
        READ_A4(afH, pA1, arH);
        STAGE_B(0, 0, tn1); STAGE_B(1, 0, tn1);
        PRIO1(); QUAD(0, 2, afL, bfB); PRIO0();

        // P3: Q3 = afH x bfB; read afL(t+2) from buf0; stage B.hi(t+2)
        GATE2(); ABAR();
        READ_A4(afL, pA0, arL);
        STAGE_B(2, 0, tn1); STAGE_B(3, 0, tn1);
        PRIO1(); QUAD(4, 2, afH, bfB); PRIO0();

        // P4: Q4 = afH x bfAo; read bfAe(t+2) from buf0; stage A.hi(t+2)
        GATE2(); ABAR();
        READ_B2(bfAe, pB0, brL);
        STAGE_A(2, 0, tn1); STAGE_A(3, 0, tn1);
        PRIO1(); QUAD(4, 0, afH, bfAo); PRIO0();
    }
    asm volatile("s_waitcnt vmcnt(0)" ::: "memory");   // drain wrapped prefetch

    // ---- epilogue: + bias, store f32 ----
    const int orow = bm + wr*64 + kgrp*4;
    const int ocol = bn + wc*32 + lrow;
#pragma unroll
    for (int n = 0; n < 4; ++n) {
        const int col = ocol + (n & 1)*16 + (n >> 1)*128;
        const float bj = bias[col];
#pragma unroll
        for (int m = 0; m < 8; ++m) {
            const int row = orow + (m & 3)*16 + (m >> 2)*128;
#pragma unroll
            for (int r = 0; r < 4; ++r)
                out[(long)(row + r) * N + col] = acc[m][n][r] + bj;
        }
    }
}

// ---------------- fallback: T = scale * x @ A^T  (one wave per row) ----------------
__global__ __launch_bounds__(64) void k_lora_T(const float* __restrict__ x,
                                               const float* __restrict__ A,
                                               float* __restrict__ T) {
    const int m = blockIdx.x;
    const int lane = threadIdx.x;
    const float* xr = x + (long)m * DIN;
    float acc[RANK];
#pragma unroll
    for (int r = 0; r < RANK; ++r) acc[r] = 0.f;
    for (int k = lane * 4; k < DIN; k += 64 * 4) {
        f32x4 xv = *(const f32x4*)(xr + k);
#pragma unroll
        for (int r = 0; r < RANK; ++r) {
            f32x4 av = *(const f32x4*)(A + (long)r * DIN + k);
            acc[r] += xv[0] * av[0] + xv[1] * av[1] + xv[2] * av[2] + xv[3] * av[3];
        }
    }
#pragma unroll
    for (int r = 0; r < RANK; ++r)
        for (int off = 32; off > 0; off >>= 1) acc[r] += __shfl_down(acc[r], off);
    if (lane == 0) {
#pragma unroll
        for (int r = 0; r < RANK; ++r) T[(long)m * RANK + r] = acc[r] * LSCALE;
    }
}

// ---------------- fallback GEMM: f32 sources, reg-staged conversion ----------------
__global__ __launch_bounds__(256) void k_gemm_nows(const float* __restrict__ x,
                                                   const float* __restrict__ W,
                                                   const float* __restrict__ bias,
                                                   const float* __restrict__ T,
                                                   const float* __restrict__ lB,
                                                   float* __restrict__ out) {
    constexpr int FBM = 128, FBN = 128, FBK = 32, K = DIN, N = DOUT;
    __shared__ __align__(16) u16 As[FBM * FBK];
    __shared__ __align__(16) u16 Bs[FBN * FBK];

    const int tid = threadIdx.x;
    const int bm = blockIdx.y * FBM;
    const int bn = blockIdx.x * FBN;
    const int lane = tid & 63;
    const int wid  = tid >> 6;
    const int wr = wid >> 1, wc = wid & 1;
    const int lrow = lane & 15;
    const int kgrp = lane >> 4;

    const int c0 = tid, c1 = tid + 256;
    const float* aS0 = x + (long)(bm + (c0 >> 2)) * K + (c0 & 3) * 8;
    const float* aS1 = x + (long)(bm + (c1 >> 2)) * K + (c1 & 3) * 8;
    const float* bS0 = W + (long)(bn + (c0 >> 2)) * K + (c0 & 3) * 8;
    const float* bS1 = W + (long)(bn + (c1 >> 2)) * K + (c1 & 3) * 8;
    u16* aD0 = As + c0 * 8;  u16* aD1 = As + c1 * 8;
    u16* bD0 = Bs + c0 * 8;  u16* bD1 = Bs + c1 * 8;

    const u16* aR = As + (wr * 64 + lrow) * FBK + kgrp * 8;
    const u16* bR = Bs + (wc * 64 + lrow) * FBK + kgrp * 8;

    f32x4 acc[4][4];
#pragma unroll
    for (int i = 0; i < 4; ++i)
#pragma unroll
        for (int j = 0; j < 4; ++j) acc[i][j] = (f32x4){0.f, 0.f, 0.f, 0.f};

    for (int k0 = 0; k0 < K; k0 += FBK) {
        f32x4 a00 = *(const f32x4*)aS0, a01 = *(const f32x4*)(aS0 + 4);
        f32x4 a10 = *(const f32x4*)aS1, a11 = *(const f32x4*)(aS1 + 4);
        f32x4 b00 = *(const f32x4*)bS0, b01 = *(const f32x4*)(bS0 + 4);
        f32x4 b10 = *(const f32x4*)bS1, b11 = *(const f32x4*)(bS1 + 4);
        aS0 += FBK; aS1 += FBK; bS0 += FBK; bS1 += FBK;
        if (k0) __syncthreads();
        *(u16x8*)aD0 = pack8(a00, a01);
        *(u16x8*)aD1 = pack8(a10, a11);
        *(u16x8*)bD0 = pack8(b00, b01);
        *(u16x8*)bD1 = pack8(b10, b11);
        __syncthreads();

        bf16x8 af[4], bf[4];
#pragma unroll
        for (int i = 0; i < 4; ++i) af[i] = *(const bf16x8*)(aR + i * 16 * FBK);
#pragma unroll
        for (int j = 0; j < 4; ++j) bf[j] = *(const bf16x8*)(bR + j * 16 * FBK);
#pragma unroll
        for (int i = 0; i < 4; ++i)
#pragma unroll
            for (int j = 0; j < 4; ++j)
                acc[i][j] = __builtin_amdgcn_mfma_f32_16x16x32_bf16(af[i], bf[j], acc[i][j], 0, 0, 0);
    }

#pragma unroll
    for (int j = 0; j < 4; ++j) {
        const int col = bn + wc * 64 + j * 16 + lrow;
        const float bj = bias[col];
        float bl[RANK];
#pragma unroll
        for (int q = 0; q < RANK; ++q) bl[q] = lB[(long)col * RANK + q];
#pragma unroll
        for (int i = 0; i < 4; ++i) {
            const int row0 = bm + wr * 64 + i * 16 + kgrp * 4;
#pragma unroll
            for (int r = 0; r < 4; ++r) {
                const int row = row0 + r;
                const float* Trow = T + (long)row * RANK;
                float s = bj;
#pragma unroll
                for (int q = 0; q < RANK; ++q) s += Trow[q] * bl[q];
                out[(long)row * N + col] = acc[i][j][r] + s;
            }
        }
    }
}

extern "C" void kernel_launch(void* const* d_in, const int* in_sizes, int n_in,
                              void* d_out, int out_size, void* d_ws, size_t ws_size,
                              hipStream_t stream) {
    const float* x    = (const float*)d_in[0];
    const float* W    = (const float*)d_in[1];
    const float* bias = (const float*)d_in[2];
    const float* lA   = (const float*)d_in[3];
    const float* lB   = (const float*)d_in[4];
    float* out = (float*)d_out;

    const size_t xb_bytes = (size_t)MTOT * DIN * sizeof(u16);   // 64 MiB
    const size_t wb_bytes = (size_t)DOUT * DIN * sizeof(u16);   // 32 MiB

    if (ws_size >= xb_bytes + wb_bytes) {
        u16* xb = (u16*)d_ws;
        u16* wb = (u16*)((char*)d_ws + xb_bytes);
        k_convert_x <<<(int)((long)MTOT * DIN / 8 / 256), 256, 0, stream>>>(x, xb);
        k_build_weff<<<(int)((long)DOUT * DIN / 8 / 256), 256, 0, stream>>>(W, lA, lB, wb);
        k_gemm_ws   <<<(MTOT / BM) * (DOUT / BN), 512, 0, stream>>>(xb, wb, bias, out);
    } else {
        float* T = (float*)d_ws;   // 512 KiB
        k_lora_T   <<<MTOT, 64, 0, stream>>>(x, lA, T);
        k_gemm_nows<<<dim3(DOUT / 128, MTOT / 128), 256, 0, stream>>>(x, W, bias, T, lB, out);
    }
}

// Round 5
// 332.192 us; speedup vs baseline: 1.1345x; 1.1345x over previous
//
#include <hip/hip_runtime.h>
#include <stdint.h>

// ---------------- problem constants (from reference) ----------------
#define DIN   4096
#define DOUT  4096
#define RANK  16
#define MTOT  8192            // 4 * 2048
#define LSCALE 2.0f           // alpha/rank = 32/16

typedef unsigned short u16;
typedef __bf16 bf16x8 __attribute__((ext_vector_type(8)));
typedef float  f32x4  __attribute__((ext_vector_type(4)));
typedef u16    u16x8  __attribute__((ext_vector_type(8)));

__device__ __forceinline__ u16 f2bf(float f) {
    uint32_t u = __builtin_bit_cast(uint32_t, f);
    u = (u + 0x7FFFu + ((u >> 16) & 1u)) >> 16;   // RNE
    return (u16)u;
}

__device__ __forceinline__ u16x8 pack8(f32x4 a, f32x4 b) {
    u16x8 o;
    o[0] = f2bf(a[0]); o[1] = f2bf(a[1]); o[2] = f2bf(a[2]); o[3] = f2bf(a[3]);
    o[4] = f2bf(b[0]); o[5] = f2bf(b[1]); o[6] = f2bf(b[2]); o[7] = f2bf(b[3]);
    return o;
}

#define GLDS16(g, l) __builtin_amdgcn_global_load_lds( \
    (const __attribute__((address_space(1))) void*)(g), \
    (__attribute__((address_space(3))) void*)(l), 16, 0, 0)

// ---------------- pass 1a: x (f32) -> xb (bf16) ----------------
__global__ __launch_bounds__(256) void k_convert_x(const float* __restrict__ x,
                                                   u16* __restrict__ xb) {
    long i = ((long)blockIdx.x * 256 + threadIdx.x) * 8;
    f32x4 a = *(const f32x4*)(x + i);
    f32x4 b = *(const f32x4*)(x + i + 4);
    *(u16x8*)(xb + i) = pack8(a, b);
}

// ---------------- pass 1b: W_eff = W + scale * B @ A  (bf16) ----------------
__global__ __launch_bounds__(256) void k_build_weff(const float* __restrict__ W,
                                                    const float* __restrict__ A,
                                                    const float* __restrict__ B,
                                                    u16* __restrict__ wb) {
    long t = (long)blockIdx.x * 256 + threadIdx.x;
    long i = t * 8;
    int o = (int)(i >> 12);        // / DIN
    int d = (int)(i & (DIN - 1));
    float sB[RANK];
#pragma unroll
    for (int r = 0; r < RANK; ++r) sB[r] = B[o * RANK + r] * LSCALE;
    f32x4 w0 = *(const f32x4*)(W + i);
    f32x4 w1 = *(const f32x4*)(W + i + 4);
#pragma unroll
    for (int r = 0; r < RANK; ++r) {
        f32x4 a0 = *(const f32x4*)(A + (long)r * DIN + d);
        f32x4 a1 = *(const f32x4*)(A + (long)r * DIN + d + 4);
        w0 += a0 * sB[r];
        w1 += a1 * sB[r];
    }
    *(u16x8*)(wb + i) = pack8(w0, w1);
}

// ---------------- main GEMM: out = xb @ wb^T + bias ----------------
// 256x256 tile, BK=64, 8 waves. READ-AHEAD pipeline (phase p reads frags for
// phase p+1's MFMA) + DEEP staging: tile t+2's data staged into the SAME
// buffer as tile t during tile t (each region staged >=2 phases after its
// last read, gated 5-7 phases later). Counted gates vmcnt(8/8/10), never 0.
// Reads:  P4(t-1): afL,bfA(t) | P1: bfB(t) | P2: afH(t) | P3: none
// MFMA:   P1: Q1=afL*bfA | P2: Q2=afL*bfB | P3: Q3=afH*bfB | P4: Q4=afH*bfA
// Stages: P1: A.hi(t+1) | P2: A.lo(t+2) | P3: B.lo+B.hi(t+2) | P4: none
#define BM 256
#define BN 256
#define BK 64
#define NT (DIN / BK)          // 64 K-tiles

#define MFMA16(d, a, b) d = __builtin_amdgcn_mfma_f32_16x16x32_bf16(a, b, d, 0, 0, 0)
#define ABAR()   asm volatile("s_barrier" ::: "memory")
#define GATE8()  asm volatile("s_waitcnt vmcnt(8)" ::: "memory")
#define GATE10() asm volatile("s_waitcnt vmcnt(10)" ::: "memory")
#define PRIO1() __builtin_amdgcn_s_setprio(1)
#define PRIO0() __builtin_amdgcn_s_setprio(0)

// 16 MFMAs, kk-OUTER: 8 independent accs between dependent acc reuses.
#define QUADK(mo, no, AF, BF) \
    _Pragma("unroll") \
    for (int kk = 0; kk < 2; ++kk) { \
        _Pragma("unroll") \
        for (int m = 0; m < 4; ++m) { \
            _Pragma("unroll") \
            for (int n = 0; n < 2; ++n) { \
                MFMA16(acc[(mo)+m][(no)+n], AF[m][kk], BF[n][kk]); \
            } \
        } \
    }

#define READ_A4(DST, P, RB) \
    _Pragma("unroll") \
    for (int m = 0; m < 4; ++m) { \
        DST[m][0] = *(const bf16x8*)((P) + (RB) + m*1024 + go0); \
        DST[m][1] = *(const bf16x8*)((P) + (RB) + m*1024 + go1); \
    }
#define READ_B2(DST, P, RB) \
    _Pragma("unroll") \
    for (int n = 0; n < 2; ++n) { \
        DST[n][0] = *(const bf16x8*)((P) + (RB) + n*1024 + go0); \
        DST[n][1] = *(const bf16x8*)((P) + (RB) + n*1024 + go1); \
    }

__global__ __launch_bounds__(512, 2) void k_gemm_ws(const u16* __restrict__ xb,
                                                    const u16* __restrict__ wb,
                                                    const float* __restrict__ bias,
                                                    float* __restrict__ out) {
    constexpr int K = DIN, N = DOUT;
    __shared__ alignas(16) u16 lds[65536];   // 128 KiB: A0 A1 B0 B1 slabs of 16384 u16

    // T1: bijective XCD swizzle (gridDim.x = 512, divisible by 8)
    const int nchunk = gridDim.x >> 3;
    const int bid = blockIdx.x;
    const int wg  = (bid & 7) * nchunk + (bid >> 3);
    const int bm  = (wg & 31) * BM;    // 32 m-tiles; consecutive wg share bn
    const int bn  = (wg >> 5) * BN;    // 16 n-tiles

    const int tid  = threadIdx.x;
    const int lane = tid & 63;
    const int wid  = tid >> 6;         // 0..7
    const int wr   = wid >> 2;         // 0..1
    const int wc   = wid & 3;          // 0..3
    const int lrow = lane & 15;
    const int kgrp = lane >> 4;        // 0..3

    // ---- staging geometry (T2: pre-swizzled global source, linear LDS dest) ----
    const int srow = tid >> 3;                       // 0..63
    const int sgl  = (tid & 7) ^ (srow & 7);
    const u16* const aSrcB = xb + (long)(bm + srow) * K + sgl * 8;
    const u16* const bSrcB = wb + (long)(bn + srow) * K + sgl * 8;

    // chunk c covers tile rows 64c..64c+63; A[buf] at buf*16384, B[buf] at 32768+buf*16384
#define STAGE_A(c, buf, kt) GLDS16(aSrcB + (long)(64*(c))*K + (kt)*BK, \
                                   lds + (buf)*16384 + (c)*4096 + tid*8)
#define STAGE_B(c, buf, kt) GLDS16(bSrcB + (long)(64*(c))*K + (kt)*BK, \
                                   lds + 32768 + (buf)*16384 + (c)*4096 + tid*8)

    // ---- fragment-read geometry (swizzled) ----
    const int go0 = (kgrp ^ (lrow & 7)) * 8;   // kk=0 granule
    const int go1 = go0 ^ 32;                  // kk=1: granule ^ 4
    const int arL = (wr*64 + lrow) * 64;       // A.lo row base (u16 units)
    const int arH = arL + 128*64;
    const int brL = (wc*32 + lrow) * 64;       // B.lo row base
    const int brH = brL + 128*64;

    const u16* const pA0 = lds;
    const u16* const pA1 = lds + 16384;
    const u16* const pB0 = lds + 32768;
    const u16* const pB1 = lds + 49152;

    f32x4 acc[8][4];
#pragma unroll
    for (int m = 0; m < 8; ++m)
#pragma unroll
        for (int n = 0; n < 4; ++n) acc[m][n] = (f32x4){0.f, 0.f, 0.f, 0.f};

    bf16x8 afL[4][2], afH[4][2], bfB[2][2], bfAe[2][2], bfAo[2][2];

    // ---- prologue: stage in exact steady-state FIFO order ----
    // [Alo0][Blo0][Bhi0][Ahi0][Alo1][Blo1][Bhi1] = 7 pairs
    STAGE_A(0, 0, 0); STAGE_A(1, 0, 0);        // A.lo(0)
    STAGE_B(0, 0, 0); STAGE_B(1, 0, 0);        // B.lo(0)
    STAGE_B(2, 0, 0); STAGE_B(3, 0, 0);        // B.hi(0)
    STAGE_A(2, 0, 0); STAGE_A(3, 0, 0);        // A.hi(0)
    STAGE_A(0, 1, 1); STAGE_A(1, 1, 1);        // A.lo(1)
    STAGE_B(0, 1, 1); STAGE_B(1, 1, 1);        // B.lo(1)
    STAGE_B(2, 1, 1); STAGE_B(3, 1, 1);        // B.hi(1)
    GATE10();                                   // retires Alo0+Blo0
    ABAR();
    READ_A4(afL, pA0, arL);                    // afL(0)
    READ_B2(bfAe, pB0, brL);                   // bfA(0)

    for (int it = 0; it < NT/2; ++it) {
        const int t   = 2*it;
        const int kt1 = t + 1;                 // <= 63
        const int kt2 = (t + 2) & (NT - 1);
        const int kt3 = (t + 3) & (NT - 1);

        // ================= even tile t (buf0), bfA = bfAe =================
        // P1: stage A.hi(t+1)->buf1; read bfB(t); Q1 = afL x bfAe
        GATE8(); ABAR();
        STAGE_A(2, 1, kt1); STAGE_A(3, 1, kt1);
        READ_B2(bfB, pB0, brH);
        PRIO1(); QUADK(0, 0, afL, bfAe); PRIO0();

        // P2: stage A.lo(t+2)->buf0; read afH(t); Q2 = afL x bfB
        GATE8(); ABAR();
        STAGE_A(0, 0, kt2); STAGE_A(1, 0, kt2);
        READ_A4(afH, pA0, arH);
        PRIO1(); QUADK(0, 2, afL, bfB); PRIO0();

        // P3: stage B.lo+B.hi(t+2)->buf0; Q3 = afH x bfB
        ABAR();
        STAGE_B(0, 0, kt2); STAGE_B(1, 0, kt2);
        STAGE_B(2, 0, kt2); STAGE_B(3, 0, kt2);
        PRIO1(); QUADK(4, 2, afH, bfB); PRIO0();

        // P4: read afL(t+1), bfAo(t+1) from buf1; Q4 = afH x bfAe
        GATE10(); ABAR();
        READ_A4(afL, pA1, arL);
        READ_B2(bfAo, pB1, brL);
        PRIO1(); QUADK(4, 0, afH, bfAe); PRIO0();

        // ================= odd tile t+1 (buf1), bfA = bfAo =================
        // P1: stage A.hi(t+2)->buf0; read bfB(t+1); Q1 = afL x bfAo
        GATE8(); ABAR();
        STAGE_A(2, 0, kt2); STAGE_A(3, 0, kt2);
        READ_B2(bfB, pB1, brH);
        PRIO1(); QUADK(0, 0, afL, bfAo); PRIO0();

        // P2: stage A.lo(t+3)->buf1; read afH(t+1); Q2 = afL x bfB
        GATE8(); ABAR();
        STAGE_A(0, 1, kt3); STAGE_A(1, 1, kt3);
        READ_A4(afH, pA1, arH);
        PRIO1(); QUADK(0, 2, afL, bfB); PRIO0();

        // P3: stage B.lo+B.hi(t+3)->buf1; Q3 = afH x bfB
        ABAR();
        STAGE_B(0, 1, kt3); STAGE_B(1, 1, kt3);
        STAGE_B(2, 1, kt3); STAGE_B(3, 1, kt3);
        PRIO1(); QUADK(4, 2, afH, bfB); PRIO0();

        // P4: read afL(t+2), bfAe(t+2) from buf0; Q4 = afH x bfAo
        GATE10(); ABAR();
        READ_A4(afL, pA0, arL);
        READ_B2(bfAe, pB0, brL);
        PRIO1(); QUADK(4, 0, afH, bfAo); PRIO0();
    }
    asm volatile("s_waitcnt vmcnt(0)" ::: "memory");   // drain wrapped prefetch

    // ---- epilogue: + bias, store f32 ----
    const int orow = bm + wr*64 + kgrp*4;
    const int ocol = bn + wc*32 + lrow;
#pragma unroll
    for (int n = 0; n < 4; ++n) {
        const int col = ocol + (n & 1)*16 + (n >> 1)*128;
        const float bj = bias[col];
#pragma unroll
        for (int m = 0; m < 8; ++m) {
            const int row = orow + (m & 3)*16 + (m >> 2)*128;
#pragma unroll
            for (int r = 0; r < 4; ++r)
                out[(long)(row + r) * N + col] = acc[m][n][r] + bj;
        }
    }
}

// ---------------- fallback: T = scale * x @ A^T  (one wave per row) ----------------
__global__ __launch_bounds__(64) void k_lora_T(const float* __restrict__ x,
                                               const float* __restrict__ A,
                                               float* __restrict__ T) {
    const int m = blockIdx.x;
    const int lane = threadIdx.x;
    const float* xr = x + (long)m * DIN;
    float acc[RANK];
#pragma unroll
    for (int r = 0; r < RANK; ++r) acc[r] = 0.f;
    for (int k = lane * 4; k < DIN; k += 64 * 4) {
        f32x4 xv = *(const f32x4*)(xr + k);
#pragma unroll
        for (int r = 0; r < RANK; ++r) {
            f32x4 av = *(const f32x4*)(A + (long)r * DIN + k);
            acc[r] += xv[0] * av[0] + xv[1] * av[1] + xv[2] * av[2] + xv[3] * av[3];
        }
    }
#pragma unroll
    for (int r = 0; r < RANK; ++r)
        for (int off = 32; off > 0; off >>= 1) acc[r] += __shfl_down(acc[r], off);
    if (lane == 0) {
#pragma unroll
        for (int r = 0; r < RANK; ++r) T[(long)m * RANK + r] = acc[r] * LSCALE;
    }
}

// ---------------- fallback GEMM: f32 sources, reg-staged conversion ----------------
__global__ __launch_bounds__(256) void k_gemm_nows(const float* __restrict__ x,
                                                   const float* __restrict__ W,
                                                   const float* __restrict__ bias,
                                                   const float* __restrict__ T,
                                                   const float* __restrict__ lB,
                                                   float* __restrict__ out) {
    constexpr int FBM = 128, FBN = 128, FBK = 32, K = DIN, N = DOUT;
    __shared__ __align__(16) u16 As[FBM * FBK];
    __shared__ __align__(16) u16 Bs[FBN * FBK];

    const int tid = threadIdx.x;
    const int bm = blockIdx.y * FBM;
    const int bn = blockIdx.x * FBN;
    const int lane = tid & 63;
    const int wid  = tid >> 6;
    const int wr = wid >> 1, wc = wid & 1;
    const int lrow = lane & 15;
    const int kgrp = lane >> 4;

    const int c0 = tid, c1 = tid + 256;
    const float* aS0 = x + (long)(bm + (c0 >> 2)) * K + (c0 & 3) * 8;
    const float* aS1 = x + (long)(bm + (c1 >> 2)) * K + (c1 & 3) * 8;
    const float* bS0 = W + (long)(bn + (c0 >> 2)) * K + (c0 & 3) * 8;
    const float* bS1 = W + (long)(bn + (c1 >> 2)) * K + (c1 & 3) * 8;
    u16* aD0 = As + c0 * 8;  u16* aD1 = As + c1 * 8;
    u16* bD0 = Bs + c0 * 8;  u16* bD1 = Bs + c1 * 8;

    const u16* aR = As + (wr * 64 + lrow) * FBK + kgrp * 8;
    const u16* bR = Bs + (wc * 64 + lrow) * FBK + kgrp * 8;

    f32x4 acc[4][4];
#pragma unroll
    for (int i = 0; i < 4; ++i)
#pragma unroll
        for (int j = 0; j < 4; ++j) acc[i][j] = (f32x4){0.f, 0.f, 0.f, 0.f};

    for (int k0 = 0; k0 < K; k0 += FBK) {
        f32x4 a00 = *(const f32x4*)aS0, a01 = *(const f32x4*)(aS0 + 4);
        f32x4 a10 = *(const f32x4*)aS1, a11 = *(const f32x4*)(aS1 + 4);
        f32x4 b00 = *(const f32x4*)bS0, b01 = *(const f32x4*)(bS0 + 4);
        f32x4 b10 = *(const f32x4*)bS1, b11 = *(const f32x4*)(bS1 + 4);
        aS0 += FBK; aS1 += FBK; bS0 += FBK; bS1 += FBK;
        if (k0) __syncthreads();
        *(u16x8*)aD0 = pack8(a00, a01);
        *(u16x8*)aD1 = pack8(a10, a11);
        *(u16x8*)bD0 = pack8(b00, b01);
        *(u16x8*)bD1 = pack8(b10, b11);
        __syncthreads();

        bf16x8 af[4], bf[4];
#pragma unroll
        for (int i = 0; i < 4; ++i) af[i] = *(const bf16x8*)(aR + i * 16 * FBK);
#pragma unroll
        for (int j = 0; j < 4; ++j) bf[j] = *(const bf16x8*)(bR + j * 16 * FBK);
#pragma unroll
        for (int i = 0; i < 4; ++i)
#pragma unroll
            for (int j = 0; j < 4; ++j)
                acc[i][j] = __builtin_amdgcn_mfma_f32_16x16x32_bf16(af[i], bf[j], acc[i][j], 0, 0, 0);
    }

#pragma unroll
    for (int j = 0; j < 4; ++j) {
        const int col = bn + wc * 64 + j * 16 + lrow;
        const float bj = bias[col];
        float bl[RANK];
#pragma unroll
        for (int q = 0; q < RANK; ++q) bl[q] = lB[(long)col * RANK + q];
#pragma unroll
        for (int i = 0; i < 4; ++i) {
            const int row0 = bm + wr * 64 + i * 16 + kgrp * 4;
#pragma unroll
            for (int r = 0; r < 4; ++r) {
                const int row = row0 + r;
                const float* Trow = T + (long)row * RANK;
                float s = bj;
#pragma unroll
                for (int q = 0; q < RANK; ++q) s += Trow[q] * bl[q];
                out[(long)row * N + col] = acc[i][j][r] + s;
            }
        }
    }
}

extern "C" void kernel_launch(void* const* d_in, const int* in_sizes, int n_in,
                              void* d_out, int out_size, void* d_ws, size_t ws_size,
                              hipStream_t stream) {
    const float* x    = (const float*)d_in[0];
    const float* W    = (const float*)d_in[1];
    const float* bias = (const float*)d_in[2];
    const float* lA   = (const float*)d_in[3];
    const float* lB   = (const float*)d_in[4];
    float* out = (float*)d_out;

    const size_t xb_bytes = (size_t)MTOT * DIN * sizeof(u16);   // 64 MiB
    const size_t wb_bytes = (size_t)DOUT * DIN * sizeof(u16);   // 32 MiB

    if (ws_size >= xb_bytes + wb_bytes) {
        u16* xb = (u16*)d_ws;
        u16* wb = (u16*)((char*)d_ws + xb_bytes);
        k_convert_x <<<(int)((long)MTOT * DIN / 8 / 256), 256, 0, stream>>>(x, xb);
        k_build_weff<<<(int)((long)DOUT * DIN / 8 / 256), 256, 0, stream>>>(W, lA, lB, wb);
        k_gemm_ws   <<<(MTOT / BM) * (DOUT / BN), 512, 0, stream>>>(xb, wb, bias, out);
    } else {
        float* T = (float*)d_ws;   // 512 KiB
        k_lora_T   <<<MTOT, 64, 0, stream>>>(x, lA, T);
        k_gemm_nows<<<dim3(DOUT / 128, MTOT / 128), 256, 0, stream>>>(x, W, bias, T, lB, out);
    }
}